// Round 23
// baseline (94.582 us; speedup 1.0000x reference)
//
#include <hip/hip_runtime.h>
#include <hip/hip_bf16.h>
#include <hip/hip_fp16.h>

#define D_IN   128
#define D_OUT  64

#define SB_A    48        // nodes per agg bucket
#define NSB_A   2084      // ceil(100000/48)
#define CAP_A   1024      // region slots (mean 768, +9 sigma)
#define CHUNK1  8192      // edges per bin chunk (512 thr x 16)
#define NPROJ   1563      // ceil(100000/64)
#define NBIN    196       // ceil(1600000/8192)

static __device__ __forceinline__ unsigned pack_h2(float a, float b) {
    __half2 h = __floats2half2_rn(a, b);
    return *reinterpret_cast<unsigned*>(&h);
}

// ---------------------------------------------------------------------------
// W prep: wT[k][c] = W[c][k]  (k-major: for fixed k, cols contiguous ->
// proj reads 8 cols with one s_load_dwordx8)
// ---------------------------------------------------------------------------
__global__ __launch_bounds__(256) void wprep_kernel(
    const float* __restrict__ Ww, float* __restrict__ wT)
{
    const int i = blockIdx.x * 256 + threadIdx.x;
    if (i < D_IN * D_OUT) {
        const int k = i >> 6;
        const int c = i & 63;
        wT[i] = Ww[c * D_IN + k];
    }
}

// ---------------------------------------------------------------------------
// prep: fused proj + bin, 512-thread blocks. Group of 9 = 8 proj tiles +
// 1 bin chunk (8192 edges). proj: 64-row tile, 8 waves x 8 cols, wT via
// scalar pipe (unroll 1 — measured best).
// ---------------------------------------------------------------------------
__global__ __launch_bounds__(512) void prep_kernel(
    const float* __restrict__ h, const float* __restrict__ wT,
    const float* __restrict__ Wb, const float* __restrict__ a,
    unsigned* __restrict__ data16, float* __restrict__ s_out, float* __restrict__ t_out,
    const int* __restrict__ e0a, const int* __restrict__ e1a,
    int* __restrict__ cursor2, unsigned int* __restrict__ region2,
    int n, int ne)
{
    __shared__ union {
        struct { float hs[64][129]; float ps[8][64]; float pt[8][64]; } p;
        struct { int cnt[NSB_A]; int basev[NSB_A]; } b;
    } sm;

    const int g   = blockIdx.x / 9;
    const int r   = blockIdx.x % 9;
    const int tid = threadIdx.x;

    if (r < 8) {
        // ------------------------- proj tile -------------------------
        const int tile = g * 8 + r;
        if (tile >= NPROJ) return;
        const int r0 = tile * 64;

        for (int i = tid; i < 64 * 32; i += 512) {
            const int row = i >> 5;
            const int kq  = i & 31;
            float4 v = make_float4(0.f, 0.f, 0.f, 0.f);
            if (r0 + row < n)
                v = ((const float4*)h)[(size_t)(r0 + row) * 32 + kq];
            sm.p.hs[row][4*kq+0] = v.x;
            sm.p.hs[row][4*kq+1] = v.y;
            sm.p.hs[row][4*kq+2] = v.z;
            sm.p.hs[row][4*kq+3] = v.w;
        }
        __syncthreads();

        const int lane = tid & 63;
        const int wv   = tid >> 6;                               // 0..7
        const int q    = __builtin_amdgcn_readfirstlane(wv);     // col octet
        const int row  = r0 + lane;
        const bool live = (row < n);

        float acc[8];
        #pragma unroll
        for (int c = 0; c < 8; ++c) acc[c] = Wb[q * 8 + c];

        #pragma unroll 1
        for (int k = 0; k < D_IN; k += 4) {
            const float h0 = sm.p.hs[lane][k + 0];
            const float h1 = sm.p.hs[lane][k + 1];
            const float h2 = sm.p.hs[lane][k + 2];
            const float h3 = sm.p.hs[lane][k + 3];
            const float* __restrict__ w0 = wT + (size_t)(k + 0) * D_OUT + q * 8;
            const float* __restrict__ w1 = wT + (size_t)(k + 1) * D_OUT + q * 8;
            const float* __restrict__ w2 = wT + (size_t)(k + 2) * D_OUT + q * 8;
            const float* __restrict__ w3 = wT + (size_t)(k + 3) * D_OUT + q * 8;
            #pragma unroll
            for (int c = 0; c < 8; ++c)
                acc[c] = fmaf(h3, w3[c],
                          fmaf(h2, w2[c],
                          fmaf(h1, w1[c],
                          fmaf(h0, w0[c], acc[c]))));
        }

        float sp = 0.f, tp = 0.f;
        #pragma unroll
        for (int c = 0; c < 8; ++c) {
            sp = fmaf(acc[c], a[q * 8 + c], sp);
            tp = fmaf(acc[c], a[D_OUT + q * 8 + c], tp);
        }
        sm.p.ps[wv][lane] = sp;
        sm.p.pt[wv][lane] = tp;

        if (live) {
            uint4 pk;
            pk.x = pack_h2(acc[0], acc[1]);
            pk.y = pack_h2(acc[2], acc[3]);
            pk.z = pack_h2(acc[4], acc[5]);
            pk.w = pack_h2(acc[6], acc[7]);
            *(uint4*)(data16 + (size_t)row * 32 + q * 4) = pk;
        }

        __syncthreads();
        if (wv == 0 && live) {
            float ss = 0.f, ts = 0.f;
            #pragma unroll
            for (int w2 = 0; w2 < 8; ++w2) {
                ss += sm.p.ps[w2][lane];
                ts += sm.p.pt[w2][lane];
            }
            s_out[row] = ss;
            t_out[row] = ts;
        }
    } else {
        // ------------------------- bin chunk -------------------------
        const int base = g * CHUNK1;

        for (int i = tid; i < NSB_A; i += 512) sm.b.cnt[i] = 0;
        __syncthreads();

        int bj[16]; unsigned rc[16];
        #pragma unroll
        for (int j = 0; j < 16; ++j) {
            const int i = base + j * 512 + tid;
            if (i < ne) {
                const int u = e0a[i];
                const int v = e1a[i];
                const int b = u / SB_A;            // magic-mul
                bj[j] = b;
                rc[j] = ((unsigned)(u - b * SB_A) << 17) | (unsigned)v;
                atomicAdd(&sm.b.cnt[b], 1);
            } else bj[j] = -1;
        }
        __syncthreads();

        for (int i = tid; i < NSB_A; i += 512) {
            const int c = sm.b.cnt[i];
            sm.b.basev[i] = (c > 0) ? atomicAdd(&cursor2[i], c) : 0;
            sm.b.cnt[i] = 0;
        }
        __syncthreads();

        #pragma unroll
        for (int j = 0; j < 16; ++j) {
            if (bj[j] >= 0) {
                const int p = sm.b.basev[bj[j]] + atomicAdd(&sm.b.cnt[bj[j]], 1);
                if (p < CAP_A) region2[(size_t)bj[j] * CAP_A + p] = rc[j];
            }
        }
    }
}

// ---------------------------------------------------------------------------
// agg (R21 config): one 256-thread block per 48-node bucket. Pass1 =
// histogram; pass2 = exp + scatter (region re-read is L2-hit); pass3 =
// 3 x (4 waves x 4 node-groups, 16 lanes/node), unroll-8.
// ---------------------------------------------------------------------------
__global__ __launch_bounds__(256) void agg_kernel(
    const int* __restrict__ cursor2, const unsigned int* __restrict__ region2,
    const float* __restrict__ s, const float* __restrict__ t,
    const unsigned* __restrict__ data16, float* __restrict__ out, int n)
{
    __shared__ int2  svw[CAP_A];
    __shared__ int   lcnt[64];
    __shared__ int   loff[64];
    __shared__ float wacc[64];
    __shared__ float s_lds[64];

    const int sb  = blockIdx.x;
    const int tid = threadIdx.x;
    const int u0  = sb * SB_A;
    if (u0 >= n) return;

    const int cnt2 = min(cursor2[sb], CAP_A);
    const unsigned int* __restrict__ reg = region2 + (size_t)sb * CAP_A;

    if (tid < 64) {
        lcnt[tid] = 0;
        wacc[tid] = 0.f;
        const int u = u0 + tid;
        s_lds[tid] = (tid < SB_A && u < n) ? s[u] : 0.f;
    }
    __syncthreads();

    // pass 1: histogram only
    for (int i = tid; i < cnt2; i += 256)
        atomicAdd(&lcnt[reg[i] >> 17], 1);
    __syncthreads();

    // single-wave exclusive scan of lcnt[64] (entries >= SB_A are zero)
    if (tid < 64) {
        const int d = lcnt[tid];
        int x = d;
        #pragma unroll
        for (int off = 1; off < 64; off <<= 1) {
            int y = __shfl_up(x, off);
            if (tid >= off) x += y;
        }
        loff[tid] = x - d;
        lcnt[tid] = 0;
    }
    __syncthreads();

    // pass 2: weight + scatter (region re-read is L2-hit)
    for (int i = tid; i < cnt2; i += 256) {
        const unsigned r = reg[i];
        const int ul = (int)(r >> 17);
        const int v  = (int)(r & 0x1FFFFu);
        const float raw = s_lds[ul] + t[v];
        const float lr  = raw > 0.f ? raw : 0.2f * raw;
        const __half wh = __float2half(__expf(lr * 0.125f));
        atomicAdd(&wacc[ul], __half2float(wh));
        const int p = loff[ul] + atomicAdd(&lcnt[ul], 1);
        svw[p] = make_int2(v << 7, (int)__half_as_ushort(wh));
    }
    __syncthreads();

    // pass 3: 3 x (4 waves x 4 node-groups), 16 lanes per node
    const int lane = tid & 63;
    const int wv   = tid >> 6;
    const int grp  = lane >> 4;
    const int c4   = lane & 15;
    const char* __restrict__ dbase = (const char*)data16 + (c4 << 3);

    #pragma unroll 1
    for (int tq = 0; tq < 3; ++tq) {
        const int ul = wv * 12 + tq * 4 + grp;
        const int u  = u0 + ul;
        const int start = loff[ul];
        const int deg   = lcnt[ul];

        float ax = 0.f, ay = 0.f, az = 0.f, aw = 0.f;
        int j = 0;
        for (; j + 8 <= deg; j += 8) {
            const int2 p0 = svw[start + j + 0];
            const int2 p1 = svw[start + j + 1];
            const int2 p2 = svw[start + j + 2];
            const int2 p3 = svw[start + j + 3];
            const int2 p4 = svw[start + j + 4];
            const int2 p5 = svw[start + j + 5];
            const int2 p6 = svw[start + j + 6];
            const int2 p7 = svw[start + j + 7];
            const uint2 q0 = *(const uint2*)(dbase + p0.x);
            const uint2 q1 = *(const uint2*)(dbase + p1.x);
            const uint2 q2 = *(const uint2*)(dbase + p2.x);
            const uint2 q3 = *(const uint2*)(dbase + p3.x);
            const uint2 q4 = *(const uint2*)(dbase + p4.x);
            const uint2 q5 = *(const uint2*)(dbase + p5.x);
            const uint2 q6 = *(const uint2*)(dbase + p6.x);
            const uint2 q7 = *(const uint2*)(dbase + p7.x);
            #define ACC_EDGE(P, Q)                                              \
            {                                                                   \
                const float w = __half2float(__ushort_as_half((unsigned short)P.y)); \
                const float2 lo = __half22float2(*(const __half2*)&Q.x);        \
                const float2 hi = __half22float2(*(const __half2*)&Q.y);        \
                ax = fmaf(w, lo.x, ax); ay = fmaf(w, lo.y, ay);                 \
                az = fmaf(w, hi.x, az); aw = fmaf(w, hi.y, aw);                 \
            }
            ACC_EDGE(p0, q0) ACC_EDGE(p1, q1) ACC_EDGE(p2, q2) ACC_EDGE(p3, q3)
            ACC_EDGE(p4, q4) ACC_EDGE(p5, q5) ACC_EDGE(p6, q6) ACC_EDGE(p7, q7)
        }
        for (; j + 4 <= deg; j += 4) {
            const int2 p0 = svw[start + j + 0];
            const int2 p1 = svw[start + j + 1];
            const int2 p2 = svw[start + j + 2];
            const int2 p3 = svw[start + j + 3];
            const uint2 q0 = *(const uint2*)(dbase + p0.x);
            const uint2 q1 = *(const uint2*)(dbase + p1.x);
            const uint2 q2 = *(const uint2*)(dbase + p2.x);
            const uint2 q3 = *(const uint2*)(dbase + p3.x);
            ACC_EDGE(p0, q0) ACC_EDGE(p1, q1) ACC_EDGE(p2, q2) ACC_EDGE(p3, q3)
        }
        for (; j < deg; ++j) {
            const int2 p0 = svw[start + j];
            const uint2 q0 = *(const uint2*)(dbase + p0.x);
            ACC_EDGE(p0, q0)
            #undef ACC_EDGE
        }

        if (ul < SB_A && u < n) {
            float4 o;
            if (deg == 0) {
                const uint2 q0 = *(const uint2*)(dbase + ((size_t)u << 7));
                const float2 lo = __half22float2(*(const __half2*)&q0.x);
                const float2 hi = __half22float2(*(const __half2*)&q0.y);
                o = make_float4(lo.x, lo.y, hi.x, hi.y);
            } else {
                const float wi = 1.0f / wacc[ul];
                o = make_float4(ax * wi, ay * wi, az * wi, aw * wi);
            }
            ((float4*)out)[(size_t)u * 16 + c4] = o;
        }
    }
}

extern "C" void kernel_launch(void* const* d_in, const int* in_sizes, int n_in,
                              void* d_out, int out_size, void* d_ws, size_t ws_size,
                              hipStream_t stream)
{
    const float* h    = (const float*)d_in[0];
    const int*   edge = (const int*)d_in[1];
    const float* Ww   = (const float*)d_in[2];
    const float* Wb   = (const float*)d_in[3];
    const float* a    = (const float*)d_in[4];

    const int n  = in_sizes[0] / D_IN;    // 100000
    const int ne = in_sizes[1] / 2;       // 1600000

    const int* e0a = edge;
    const int* e1a = edge + ne;
    float* out = (float*)d_out;

    char* wsp = (char*)d_ws;
    unsigned* data16 = (unsigned*)wsp; wsp += (size_t)n * 32 * sizeof(unsigned);
    float* s       = (float*)wsp;  wsp += (size_t)n * sizeof(float);
    float* t       = (float*)wsp;  wsp += (size_t)n * sizeof(float);
    int*   cursor2 = (int*)wsp;    wsp += 2560 * sizeof(int);
    float* wT      = (float*)wsp;  wsp += (size_t)D_IN * D_OUT * sizeof(float);
    unsigned int* region2 = (unsigned int*)wsp; wsp += (size_t)NSB_A * CAP_A * sizeof(unsigned int);

    hipMemsetAsync(cursor2, 0, 2560 * sizeof(int), stream);

    wprep_kernel<<<(D_IN * D_OUT + 255) / 256, 256, 0, stream>>>(Ww, wT);

    prep_kernel<<<NBIN * 9, 512, 0, stream>>>(
        h, wT, Wb, a, data16, s, t, e0a, e1a, cursor2, region2, n, ne);

    agg_kernel<<<NSB_A, 256, 0, stream>>>(
        cursor2, region2, s, t, data16, out, n);
}

// Round 24
// 89.970 us; speedup vs baseline: 1.0513x; 1.0513x over previous
//
#include <hip/hip_runtime.h>
#include <hip/hip_bf16.h>
#include <hip/hip_fp16.h>

#define D_IN   128
#define D_OUT  64

#define SB_A    48        // nodes per agg bucket
#define NSB_A   2084      // ceil(100000/48)
#define CAP_A   1024      // region slots (mean 768, +9 sigma)
#define CHUNK1  4096      // edges per bin chunk (512 thr x 8)
#define NPROJ   1563      // ceil(100000/64)
#define NBIN    391       // ceil(1600000/4096)

static __device__ __forceinline__ unsigned pack_h2(float a, float b) {
    __half2 h = __floats2half2_rn(a, b);
    return *reinterpret_cast<unsigned*>(&h);
}

// ---------------------------------------------------------------------------
// W prep: wT[k][c] = W[c][k]  (k-major: for fixed k, cols contiguous ->
// the fused proj phase reads 8 cols with one s_load_dwordx8)
// ---------------------------------------------------------------------------
__global__ __launch_bounds__(256) void wprep_kernel(
    const float* __restrict__ Ww, float* __restrict__ wT)
{
    const int i = blockIdx.x * 256 + threadIdx.x;
    if (i < D_IN * D_OUT) {
        const int k = i >> 6;
        const int c = i & 63;
        wT[i] = Ww[c * D_IN + k];
    }
}

// ---------------------------------------------------------------------------
// prep: fused proj + bin1, 512-thread blocks (4 blocks/CU -> real overlap).
// r = bid%5: r<4 -> proj 64-row tile (8 waves x 8 cols, wT via scalar pipe);
// r==4 -> bin chunk of 4096 edges -> 2084 fine regions.
// ---------------------------------------------------------------------------
__global__ __launch_bounds__(512) void prep_kernel(
    const float* __restrict__ h, const float* __restrict__ wT,
    const float* __restrict__ Wb, const float* __restrict__ a,
    unsigned* __restrict__ data16, float* __restrict__ s_out, float* __restrict__ t_out,
    const int* __restrict__ e0a, const int* __restrict__ e1a,
    int* __restrict__ cursor2, unsigned int* __restrict__ region2,
    int n, int ne)
{
    __shared__ union {
        struct { float hs[64][129]; float ps[8][64]; float pt[8][64]; } p;
        struct { int cnt[NSB_A]; int basev[NSB_A]; } b;
    } sm;

    const int g   = blockIdx.x / 5;
    const int r   = blockIdx.x % 5;
    const int tid = threadIdx.x;

    if (r < 4) {
        // ------------------------- proj tile -------------------------
        const int tile = g * 4 + r;
        if (tile >= NPROJ) return;
        const int r0 = tile * 64;

        for (int i = tid; i < 64 * 32; i += 512) {
            const int row = i >> 5;
            const int kq  = i & 31;
            float4 v = make_float4(0.f, 0.f, 0.f, 0.f);
            if (r0 + row < n)
                v = ((const float4*)h)[(size_t)(r0 + row) * 32 + kq];
            sm.p.hs[row][4*kq+0] = v.x;
            sm.p.hs[row][4*kq+1] = v.y;
            sm.p.hs[row][4*kq+2] = v.z;
            sm.p.hs[row][4*kq+3] = v.w;
        }
        __syncthreads();

        const int lane = tid & 63;
        const int wv   = tid >> 6;                               // 0..7
        const int q    = __builtin_amdgcn_readfirstlane(wv);     // col octet
        const int row  = r0 + lane;
        const bool live = (row < n);

        float acc[8];
        #pragma unroll
        for (int c = 0; c < 8; ++c) acc[c] = Wb[q * 8 + c];

        #pragma unroll 1
        for (int k = 0; k < D_IN; k += 4) {
            const float h0 = sm.p.hs[lane][k + 0];
            const float h1 = sm.p.hs[lane][k + 1];
            const float h2 = sm.p.hs[lane][k + 2];
            const float h3 = sm.p.hs[lane][k + 3];
            const float* __restrict__ w0 = wT + (size_t)(k + 0) * D_OUT + q * 8;
            const float* __restrict__ w1 = wT + (size_t)(k + 1) * D_OUT + q * 8;
            const float* __restrict__ w2 = wT + (size_t)(k + 2) * D_OUT + q * 8;
            const float* __restrict__ w3 = wT + (size_t)(k + 3) * D_OUT + q * 8;
            #pragma unroll
            for (int c = 0; c < 8; ++c)
                acc[c] = fmaf(h3, w3[c],
                          fmaf(h2, w2[c],
                          fmaf(h1, w1[c],
                          fmaf(h0, w0[c], acc[c]))));
        }

        float sp = 0.f, tp = 0.f;
        #pragma unroll
        for (int c = 0; c < 8; ++c) {
            sp = fmaf(acc[c], a[q * 8 + c], sp);
            tp = fmaf(acc[c], a[D_OUT + q * 8 + c], tp);
        }
        sm.p.ps[wv][lane] = sp;
        sm.p.pt[wv][lane] = tp;

        if (live) {
            uint4 pk;
            pk.x = pack_h2(acc[0], acc[1]);
            pk.y = pack_h2(acc[2], acc[3]);
            pk.z = pack_h2(acc[4], acc[5]);
            pk.w = pack_h2(acc[6], acc[7]);
            *(uint4*)(data16 + (size_t)row * 32 + q * 4) = pk;
        }

        __syncthreads();
        if (wv == 0 && live) {
            float ss = 0.f, ts = 0.f;
            #pragma unroll
            for (int w2 = 0; w2 < 8; ++w2) {
                ss += sm.p.ps[w2][lane];
                ts += sm.p.pt[w2][lane];
            }
            s_out[row] = ss;
            t_out[row] = ts;
        }
    } else {
        // ------------------------- bin chunk -------------------------
        const int base = g * CHUNK1;

        for (int i = tid; i < NSB_A; i += 512) sm.b.cnt[i] = 0;
        __syncthreads();

        int bj[8]; unsigned rc[8];
        #pragma unroll
        for (int j = 0; j < 8; ++j) {
            const int i = base + j * 512 + tid;
            if (i < ne) {
                const int u = e0a[i];
                const int v = e1a[i];
                const int b = u / SB_A;            // magic-mul
                bj[j] = b;
                rc[j] = ((unsigned)(u - b * SB_A) << 17) | (unsigned)v;
                atomicAdd(&sm.b.cnt[b], 1);
            } else bj[j] = -1;
        }
        __syncthreads();

        for (int i = tid; i < NSB_A; i += 512) {
            const int c = sm.b.cnt[i];
            sm.b.basev[i] = (c > 0) ? atomicAdd(&cursor2[i], c) : 0;
            sm.b.cnt[i] = 0;
        }
        __syncthreads();

        #pragma unroll
        for (int j = 0; j < 8; ++j) {
            if (bj[j] >= 0) {
                const int p = sm.b.basev[bj[j]] + atomicAdd(&sm.b.cnt[bj[j]], 1);
                if (p < CAP_A) region2[(size_t)bj[j] * CAP_A + p] = rc[j];
            }
        }
    }
}

// ---------------------------------------------------------------------------
// agg: one 256-thread block per 48-node bucket (2084 blocks -> 8.1/CU).
// Pass1 histogram, pass2 exp+scatter, pass3 = 3 x (4 waves x 4 node-groups,
// 16 lanes/node), unroll-8.
// ---------------------------------------------------------------------------
__global__ __launch_bounds__(256) void agg_kernel(
    const int* __restrict__ cursor2, const unsigned int* __restrict__ region2,
    const float* __restrict__ s, const float* __restrict__ t,
    const unsigned* __restrict__ data16, float* __restrict__ out, int n)
{
    __shared__ int2  svw[CAP_A];
    __shared__ int   lcnt[64];
    __shared__ int   loff[64];
    __shared__ float wacc[64];
    __shared__ float s_lds[64];

    const int sb  = blockIdx.x;
    const int tid = threadIdx.x;
    const int u0  = sb * SB_A;
    if (u0 >= n) return;

    const int cnt2 = min(cursor2[sb], CAP_A);
    const unsigned int* __restrict__ reg = region2 + (size_t)sb * CAP_A;

    if (tid < 64) {
        lcnt[tid] = 0;
        wacc[tid] = 0.f;
        const int u = u0 + tid;
        s_lds[tid] = (tid < SB_A && u < n) ? s[u] : 0.f;
    }
    __syncthreads();

    // pass 1: histogram only
    for (int i = tid; i < cnt2; i += 256)
        atomicAdd(&lcnt[reg[i] >> 17], 1);
    __syncthreads();

    // single-wave exclusive scan of lcnt[64] (entries >= SB_A are zero)
    if (tid < 64) {
        const int d = lcnt[tid];
        int x = d;
        #pragma unroll
        for (int off = 1; off < 64; off <<= 1) {
            int y = __shfl_up(x, off);
            if (tid >= off) x += y;
        }
        loff[tid] = x - d;
        lcnt[tid] = 0;
    }
    __syncthreads();

    // pass 2: weight + scatter (region re-read is L2-hit)
    for (int i = tid; i < cnt2; i += 256) {
        const unsigned r = reg[i];
        const int ul = (int)(r >> 17);
        const int v  = (int)(r & 0x1FFFFu);
        const float raw = s_lds[ul] + t[v];
        const float lr  = raw > 0.f ? raw : 0.2f * raw;
        const __half wh = __float2half(__expf(lr * 0.125f));
        atomicAdd(&wacc[ul], __half2float(wh));
        const int p = loff[ul] + atomicAdd(&lcnt[ul], 1);
        svw[p] = make_int2(v << 7, (int)__half_as_ushort(wh));
    }
    __syncthreads();

    // pass 3: 3 x (4 waves x 4 node-groups), 16 lanes per node
    const int lane = tid & 63;
    const int wv   = tid >> 6;
    const int grp  = lane >> 4;
    const int c4   = lane & 15;
    const char* __restrict__ dbase = (const char*)data16 + (c4 << 3);

    #pragma unroll 1
    for (int tq = 0; tq < 3; ++tq) {
        const int ul = wv * 12 + tq * 4 + grp;
        const int u  = u0 + ul;
        const int start = loff[ul];
        const int deg   = lcnt[ul];

        float ax = 0.f, ay = 0.f, az = 0.f, aw = 0.f;
        int j = 0;
        for (; j + 8 <= deg; j += 8) {
            const int2 p0 = svw[start + j + 0];
            const int2 p1 = svw[start + j + 1];
            const int2 p2 = svw[start + j + 2];
            const int2 p3 = svw[start + j + 3];
            const int2 p4 = svw[start + j + 4];
            const int2 p5 = svw[start + j + 5];
            const int2 p6 = svw[start + j + 6];
            const int2 p7 = svw[start + j + 7];
            const uint2 q0 = *(const uint2*)(dbase + p0.x);
            const uint2 q1 = *(const uint2*)(dbase + p1.x);
            const uint2 q2 = *(const uint2*)(dbase + p2.x);
            const uint2 q3 = *(const uint2*)(dbase + p3.x);
            const uint2 q4 = *(const uint2*)(dbase + p4.x);
            const uint2 q5 = *(const uint2*)(dbase + p5.x);
            const uint2 q6 = *(const uint2*)(dbase + p6.x);
            const uint2 q7 = *(const uint2*)(dbase + p7.x);
            #define ACC_EDGE(P, Q)                                              \
            {                                                                   \
                const float w = __half2float(__ushort_as_half((unsigned short)P.y)); \
                const float2 lo = __half22float2(*(const __half2*)&Q.x);        \
                const float2 hi = __half22float2(*(const __half2*)&Q.y);        \
                ax = fmaf(w, lo.x, ax); ay = fmaf(w, lo.y, ay);                 \
                az = fmaf(w, hi.x, az); aw = fmaf(w, hi.y, aw);                 \
            }
            ACC_EDGE(p0, q0) ACC_EDGE(p1, q1) ACC_EDGE(p2, q2) ACC_EDGE(p3, q3)
            ACC_EDGE(p4, q4) ACC_EDGE(p5, q5) ACC_EDGE(p6, q6) ACC_EDGE(p7, q7)
        }
        for (; j + 4 <= deg; j += 4) {
            const int2 p0 = svw[start + j + 0];
            const int2 p1 = svw[start + j + 1];
            const int2 p2 = svw[start + j + 2];
            const int2 p3 = svw[start + j + 3];
            const uint2 q0 = *(const uint2*)(dbase + p0.x);
            const uint2 q1 = *(const uint2*)(dbase + p1.x);
            const uint2 q2 = *(const uint2*)(dbase + p2.x);
            const uint2 q3 = *(const uint2*)(dbase + p3.x);
            ACC_EDGE(p0, q0) ACC_EDGE(p1, q1) ACC_EDGE(p2, q2) ACC_EDGE(p3, q3)
        }
        for (; j < deg; ++j) {
            const int2 p0 = svw[start + j];
            const uint2 q0 = *(const uint2*)(dbase + p0.x);
            ACC_EDGE(p0, q0)
            #undef ACC_EDGE
        }

        if (ul < SB_A && u < n) {
            float4 o;
            if (deg == 0) {
                const uint2 q0 = *(const uint2*)(dbase + ((size_t)u << 7));
                const float2 lo = __half22float2(*(const __half2*)&q0.x);
                const float2 hi = __half22float2(*(const __half2*)&q0.y);
                o = make_float4(lo.x, lo.y, hi.x, hi.y);
            } else {
                const float wi = 1.0f / wacc[ul];
                o = make_float4(ax * wi, ay * wi, az * wi, aw * wi);
            }
            ((float4*)out)[(size_t)u * 16 + c4] = o;
        }
    }
}

extern "C" void kernel_launch(void* const* d_in, const int* in_sizes, int n_in,
                              void* d_out, int out_size, void* d_ws, size_t ws_size,
                              hipStream_t stream)
{
    const float* h    = (const float*)d_in[0];
    const int*   edge = (const int*)d_in[1];
    const float* Ww   = (const float*)d_in[2];
    const float* Wb   = (const float*)d_in[3];
    const float* a    = (const float*)d_in[4];

    const int n  = in_sizes[0] / D_IN;    // 100000
    const int ne = in_sizes[1] / 2;       // 1600000

    const int* e0a = edge;
    const int* e1a = edge + ne;
    float* out = (float*)d_out;

    char* wsp = (char*)d_ws;
    unsigned* data16 = (unsigned*)wsp; wsp += (size_t)n * 32 * sizeof(unsigned);
    float* s       = (float*)wsp;  wsp += (size_t)n * sizeof(float);
    float* t       = (float*)wsp;  wsp += (size_t)n * sizeof(float);
    int*   cursor2 = (int*)wsp;    wsp += 2560 * sizeof(int);
    float* wT      = (float*)wsp;  wsp += (size_t)D_IN * D_OUT * sizeof(float);
    unsigned int* region2 = (unsigned int*)wsp; wsp += (size_t)NSB_A * CAP_A * sizeof(unsigned int);

    hipMemsetAsync(cursor2, 0, 2560 * sizeof(int), stream);

    wprep_kernel<<<(D_IN * D_OUT + 255) / 256, 256, 0, stream>>>(Ww, wT);

    prep_kernel<<<NBIN * 5, 512, 0, stream>>>(
        h, wT, Wb, a, data16, s, t, e0a, e1a, cursor2, region2, n, ne);

    agg_kernel<<<NSB_A, 256, 0, stream>>>(
        cursor2, region2, s, t, data16, out, n);
}